// Round 11
// baseline (546.168 us; speedup 1.0000x reference)
//
#include <hip/hip_runtime.h>

#define NN 100000
#define RR 8
#define BB 8
#define DD 128
#define EE 800000
#define KT 1152                  // 128 (root) + 8*128 (relations)
#define NBLK 782                 // ceil(NN/128)
#define NSEG2 (NBLK * 1024)      // 800768 padded segment keys
#define AGSTR 132                // Aagg stride: 66 dwords/row == 2 mod 32 (R8 zero-conflict class)
#define NCVT 6250                // k_pre partition: cvt blocks
#define NCNT 3125                // k_pre partition: cnt blocks
#define NPB  576                 // k_pre partition: prepB blocks (each layer)

typedef __attribute__((ext_vector_type(8))) __bf16 bf16x8;
typedef __attribute__((ext_vector_type(4))) float f32x4;
typedef __attribute__((ext_vector_type(4))) unsigned int u32x4;

__device__ __forceinline__ unsigned short f2bf(float f) {
    unsigned u = __float_as_uint(f);
    u += 0x7fffu + ((u >> 16) & 1u);          // round-to-nearest-even
    return (unsigned short)(u >> 16);
}
__device__ __forceinline__ float bf2f(unsigned short h) {
    return __uint_as_float(((unsigned)h) << 16);
}

// ---------------------------------------------------------------------------
// prepB body: BT[o][k] bf16 hi/lo; k<128 -> root, else W[r][i][o]
// ---------------------------------------------------------------------------
__device__ __forceinline__ void prepB_body(int idx,
                                           const float* __restrict__ root,
                                           const float* __restrict__ comp,
                                           const float* __restrict__ basis,
                                           unsigned short* __restrict__ Bhi,
                                           unsigned short* __restrict__ Blo) {
    if (idx >= DD * KT) return;
    int o = idx / KT, k = idx - o * KT;
    float v;
    if (k < DD) {
        v = root[k * DD + o];
    } else {
        int r = (k - DD) >> 7, i = (k - DD) & 127;
        float s = 0.f;
#pragma unroll
        for (int b = 0; b < BB; ++b)
            s += comp[r * BB + b] * basis[((size_t)b * DD + i) * DD + o];
        v = s;
    }
    unsigned short hi = f2bf(v);
    Bhi[idx] = hi;
    Blo[idx] = f2bf(v - bf2f(hi));
}

// ---------------------------------------------------------------------------
// Fused preprocessing: cvt | cnt | prepB1 | prepB2 partitioned by blockIdx.
// ---------------------------------------------------------------------------
__global__ __launch_bounds__(256) void k_pre(
    const float* __restrict__ x, unsigned short* __restrict__ xh,
    const int* __restrict__ ei, const int* __restrict__ et, int* __restrict__ cnt,
    const float* __restrict__ root1, const float* __restrict__ comp1,
    const float* __restrict__ basis1,
    unsigned short* __restrict__ Bhi1, unsigned short* __restrict__ Blo1,
    const float* __restrict__ root2, const float* __restrict__ comp2,
    const float* __restrict__ basis2,
    unsigned short* __restrict__ Bhi2, unsigned short* __restrict__ Blo2)
{
    const int blk = blockIdx.x, tid = threadIdx.x;
    if (blk < NCVT) {
        int i = blk * 256 + tid;                 // over NN*DD/8 = 1,600,000
        f32x4 a = ((const f32x4*)x)[2 * i];
        f32x4 b = ((const f32x4*)x)[2 * i + 1];
        u32x4 o;
        o[0] = (unsigned)f2bf(a[0]) | ((unsigned)f2bf(a[1]) << 16);
        o[1] = (unsigned)f2bf(a[2]) | ((unsigned)f2bf(a[3]) << 16);
        o[2] = (unsigned)f2bf(b[0]) | ((unsigned)f2bf(b[1]) << 16);
        o[3] = (unsigned)f2bf(b[2]) | ((unsigned)f2bf(b[3]) << 16);
        ((u32x4*)xh)[i] = o;
    } else if (blk < NCVT + NCNT) {
        int e = (blk - NCVT) * 256 + tid;
        if (e < EE) {
            int d = ei[EE + e];
            atomicAdd(&cnt[(d >> 7) * 1024 + et[e] * 128 + (d & 127)], 1);
        }
    } else if (blk < NCVT + NCNT + NPB) {
        prepB_body((blk - NCVT - NCNT) * 256 + tid, root1, comp1, basis1, Bhi1, Blo1);
    } else {
        prepB_body((blk - NCVT - NCNT - NPB) * 256 + tid, root2, comp2, basis2, Bhi2, Blo2);
    }
}

__global__ __launch_bounds__(256) void k_scan_local(const int* __restrict__ cnt,
                                                    int* __restrict__ loc,
                                                    int* __restrict__ bsum) {
    __shared__ int tmp[256];
    int t = threadIdx.x, i = blockIdx.x * 256 + t;
    int v = cnt[i];
    tmp[t] = v; __syncthreads();
    int val = v;
#pragma unroll
    for (int d = 1; d < 256; d <<= 1) {
        int a = (t >= d) ? tmp[t - d] : 0;
        __syncthreads();
        val += a; tmp[t] = val;
        __syncthreads();
    }
    loc[i] = val - v;
    if (t == 255) bsum[blockIdx.x] = val;
}

__global__ void k_scan_bsum(const int* __restrict__ bsum, int* __restrict__ boff) {
    __shared__ int tmp[256];
    const int NB = NSEG2 / 256;             // 3128
    const int CH = 13;                      // 256*13 >= 3128
    int t = threadIdx.x;
    int base = t * CH, s = 0;
    for (int j = 0; j < CH; ++j) { int idx = base + j; if (idx < NB) s += bsum[idx]; }
    tmp[t] = s; __syncthreads();
    int val = s;
#pragma unroll
    for (int d = 1; d < 256; d <<= 1) {
        int a = (t >= d) ? tmp[t - d] : 0;
        __syncthreads();
        val += a; tmp[t] = val;
        __syncthreads();
    }
    int run = val - s;
    for (int j = 0; j < CH; ++j) { int idx = base + j; if (idx < NB) { boff[idx] = run; run += bsum[idx]; } }
}

__global__ __launch_bounds__(256) void k_scan_add(int* __restrict__ loc,
                                                  const int* __restrict__ boff) {
    int i = blockIdx.x * 256 + threadIdx.x;
    loc[i] += boff[i >> 8];
}

// scatter: pack src; uses segoff as its cursor (post-scatter segoff = segment END,
// segments contiguous in key order so begin[k] = end[k-1])
__global__ __launch_bounds__(256) void k_scatter(const int* __restrict__ ei,
                                                 const int* __restrict__ et,
                                                 int* __restrict__ segoff,
                                                 int* __restrict__ spk) {
    int e = blockIdx.x * 256 + threadIdx.x;
    if (e < EE) {
        int d = ei[EE + e];
        int key = (d >> 7) * 1024 + et[e] * 128 + (d & 127);
        int pos = atomicAdd(&segoff[key], 1);
        spk[pos] = ei[e];
    }
}

// ---------------------------------------------------------------------------
// Fused agg + GEMM, R10 = R9 (the 176.5 µs WIN) with constants-only changes:
//  * AGSTR 136 -> 132: Aagg dword stride 66 == 2 mod 32 — the stride class
//    R8 measured at ZERO conflicts (R9's 68-dword class cost 2.4M cycles).
//  * sbeg LDS tile deleted: per relation beg/cs come from two INDEPENDENT
//    segend loads (1 round trip, 8x/block, amortized) — saves 4.1 KB.
//  * LDS 55.3 -> 50.2 KB => 3 blocks/CU (was 2): +50% wave-level latency
//    hiding on what the R9 counters show is a pure-stall-dominated kernel
//    (MFMA-busy ~24us, VALU ~41us, dur 177us).
//  Structure (proven R9): per relation BOTH 32-col agg passes back-to-back
//  (iron law #2: temporal adjacency keeps pass 2 L2-hot), full-width Aagg,
//  then 4 consecutive k-steps; B double-staged reg->LDS pipeline (ASTR=32 +
//  XOR quad-swizzle, measured zero-conflict); agg transients die before any
//  MFMA (iron law #1; WRITE_SIZE is the spill tripwire).
// ---------------------------------------------------------------------------
template <bool WRITE_H1>
__global__ __launch_bounds__(256, 3) void k_gemm(
    const unsigned short* __restrict__ xh,
    const unsigned short* __restrict__ Bhi,
    const unsigned short* __restrict__ Blo,
    const float* __restrict__ bias,
    const int* __restrict__ spk,
    const int* __restrict__ segend,     // post-scatter segoff = segment ends
    unsigned short* __restrict__ h1h,
    float* __restrict__ outf)
{
    __shared__ unsigned short Aagg[128 * AGSTR]; // 33,792 B
    __shared__ unsigned short Bhs[128 * 32];     //  8,192 B
    __shared__ unsigned short Bls[128 * 32];     //  8,192 B  (total 50,176)

    const int tid = threadIdx.x;
    const int b = blockIdx.x;
    const int M0 = b * 128;
    const int gbase = b * 1024;

    const int wave = tid >> 6, lane = tid & 63;
    const int quad = lane >> 4, lm = lane & 15;
    const int node = tid >> 1, half = tid & 1;

    f32x4 acc[2][8];
#pragma unroll
    for (int a = 0; a < 2; ++a)
#pragma unroll
        for (int n = 0; n < 8; ++n) acc[a][n] = (f32x4){0.f, 0.f, 0.f, 0.f};

    // ---- B pipeline: regs always hold the NEXT tile. 16 VGPR.
    const int bro = tid >> 2;                    // 0..63 (also stages 64+bro)
    const int bq = tid & 3;                      // 16B quad within 64B row
    const int bsw = bq ^ ((bro >> 1) & 3);       // swizzled write slot
    const int brd = lm * 32 + (quad ^ ((lm >> 1) & 3)) * 8;  // swizzled read base
    u32x4 bh0, bh1, bl0, bl1;

    auto bload = [&](int k0) {
        bh0 = *(const u32x4*)(Bhi + (size_t)bro * KT + k0 + bq * 8);
        bl0 = *(const u32x4*)(Blo + (size_t)bro * KT + k0 + bq * 8);
        bh1 = *(const u32x4*)(Bhi + (size_t)(64 + bro) * KT + k0 + bq * 8);
        bl1 = *(const u32x4*)(Blo + (size_t)(64 + bro) * KT + k0 + bq * 8);
    };
    auto bwrite = [&]() {
        *(u32x4*)&Bhs[bro * 32 + bsw * 8] = bh0;
        *(u32x4*)&Bls[bro * 32 + bsw * 8] = bl0;
        *(u32x4*)&Bhs[(64 + bro) * 32 + bsw * 8] = bh1;
        *(u32x4*)&Bls[(64 + bro) * 32 + bsw * 8] = bl1;
    };

    auto kstep = [&](bf16x8 af0, bf16x8 af1, int k0next, bool tail) {
#pragma unroll
        for (int nt = 0; nt < 8; ++nt) {
            bf16x8 bh = __builtin_bit_cast(bf16x8, *(const u32x4*)&Bhs[nt * 512 + brd]);
            bf16x8 bl = __builtin_bit_cast(bf16x8, *(const u32x4*)&Bls[nt * 512 + brd]);
            acc[0][nt] = __builtin_amdgcn_mfma_f32_16x16x32_bf16(af0, bh, acc[0][nt], 0, 0, 0);
            acc[0][nt] = __builtin_amdgcn_mfma_f32_16x16x32_bf16(af0, bl, acc[0][nt], 0, 0, 0);
            acc[1][nt] = __builtin_amdgcn_mfma_f32_16x16x32_bf16(af1, bh, acc[1][nt], 0, 0, 0);
            acc[1][nt] = __builtin_amdgcn_mfma_f32_16x16x32_bf16(af1, bl, acc[1][nt], 0, 0, 0);
        }
        if (tail) return;
        __syncthreads();                 // all waves done reading tile t (and Aagg)
        bwrite();                        // LDS <- tile t+1
        if (k0next >= 0) bload(k0next);  // regs <- tile t+2 (flies past barrier)
        __syncthreads();                 // tile t+1 visible
    };

    // ---- prologue: tile 0 -> LDS, tile 1 -> regs
    bload(0);
    bwrite();
    bload(32);

    // root-phase A-fragments (direct global, clamped rows; masked in epilogue)
    int r0 = M0 + wave * 32 + lm;      if (r0 > NN - 1) r0 = NN - 1;
    int r1 = M0 + wave * 32 + 16 + lm; if (r1 > NN - 1) r1 = NN - 1;
    const unsigned short* pa0 = xh + (size_t)r0 * DD + quad * 8;
    const unsigned short* pa1 = xh + (size_t)r1 * DD + quad * 8;

    __syncthreads();                     // tile 0 visible

    // ---- root phase: 4 k-steps
#pragma unroll
    for (int ks = 0; ks < 4; ++ks) {
        bf16x8 af0 = __builtin_bit_cast(bf16x8, *(const u32x4*)(pa0 + ks * 32));
        bf16x8 af1 = __builtin_bit_cast(bf16x8, *(const u32x4*)(pa1 + ks * 32));
        const int k0n = (ks < 2) ? (ks + 2) * 32 : DD + (ks - 2) * 32;
        kstep(af0, af1, k0n, false);
    }

    // ---- relation phase: agg both halves back-to-back, then 4 k-steps
    for (int r = 0; r < RR; ++r) {
        const int gix = gbase + r * 128 + node;
        // two independent loads -> single round trip
        const int beg = (gix == 0) ? 0 : segend[gix - 1];
        const int cs = segend[gix] - beg;

        // (prev kstep's trailing barrier separates these Aagg writes from
        //  relation r-1's MFMA reads)
#pragma unroll
        for (int p = 0; p < 2; ++p) {
            const int coff = half * 64 + p * 32;   // thread's 32-col slice
            float vlo[16], vhi[16];
#pragma unroll
            for (int j = 0; j < 16; ++j) { vlo[j] = 0.f; vhi[j] = 0.f; }

            for (int t = 0; t < cs; ++t) {
                const int sp = spk[beg + t];
                const u32x4* ps = (const u32x4*)(xh + (size_t)sp * DD + coff);
                u32x4 a0 = ps[0], a1 = ps[1], a2 = ps[2], a3 = ps[3];
#pragma unroll
                for (int w = 0; w < 4; ++w) {
                    vlo[w]      += __uint_as_float(a0[w] << 16);
                    vhi[w]      += __uint_as_float(a0[w] & 0xFFFF0000u);
                    vlo[4 + w]  += __uint_as_float(a1[w] << 16);
                    vhi[4 + w]  += __uint_as_float(a1[w] & 0xFFFF0000u);
                    vlo[8 + w]  += __uint_as_float(a2[w] << 16);
                    vhi[8 + w]  += __uint_as_float(a2[w] & 0xFFFF0000u);
                    vlo[12 + w] += __uint_as_float(a3[w] << 16);
                    vhi[12 + w] += __uint_as_float(a3[w] & 0xFFFF0000u);
                }
            }

            const float inv = 1.0f / (float)(cs > 1 ? cs : 1);
            unsigned pk[16];
#pragma unroll
            for (int j = 0; j < 16; ++j)
                pk[j] = (unsigned)f2bf(vlo[j] * inv) | ((unsigned)f2bf(vhi[j] * inv) << 16);
            unsigned short* pw = &Aagg[node * AGSTR + coff];
            *(u32x4*)(pw + 0)  = (u32x4){pk[0],  pk[1],  pk[2],  pk[3]};
            *(u32x4*)(pw + 8)  = (u32x4){pk[4],  pk[5],  pk[6],  pk[7]};
            *(u32x4*)(pw + 16) = (u32x4){pk[8],  pk[9],  pk[10], pk[11]};
            *(u32x4*)(pw + 24) = (u32x4){pk[12], pk[13], pk[14], pk[15]};
        }

        __syncthreads();                 // Aagg ready (B tile already staged)

        // 4 k-steps, A from Aagg
#pragma unroll
        for (int s = 0; s < 4; ++s) {
            bf16x8 af0 = __builtin_bit_cast(bf16x8,
                *(const u32x4*)&Aagg[(wave * 32 + lm) * AGSTR + s * 32 + quad * 8]);
            bf16x8 af1 = __builtin_bit_cast(bf16x8,
                *(const u32x4*)&Aagg[(wave * 32 + 16 + lm) * AGSTR + s * 32 + quad * 8]);
            const bool tail = (r == RR - 1) && (s == 3);
            const int k0n = (s < 2) ? DD + r * 128 + (s + 2) * 32
                          : ((r < RR - 1) ? DD + (r + 1) * 128 + (s - 2) * 32 : -1);
            kstep(af0, af1, k0n, tail);
        }
    }

    // ---- epilogue (C/D: col=lane&15, row=quad*4+reg)
#pragma unroll
    for (int mt = 0; mt < 2; ++mt) {
#pragma unroll
        for (int nt = 0; nt < 8; ++nt) {
            const float bvn = bias[nt * 16 + lm];
#pragma unroll
            for (int rg = 0; rg < 4; ++rg) {
                int row = M0 + wave * 32 + mt * 16 + quad * 4 + rg;
                if (row < NN) {
                    int col = nt * 16 + lm;
                    float v = acc[mt][nt][rg] + bvn;
                    if (WRITE_H1) h1h[(size_t)row * DD + col] = f2bf(fmaxf(v, 0.f));
                    else          outf[(size_t)row * DD + col] = v;
                }
            }
        }
    }
}

// ---------------------------------------------------------------------------

extern "C" void kernel_launch(void* const* d_in, const int* in_sizes, int n_in,
                              void* d_out, int out_size, void* d_ws, size_t ws_size,
                              hipStream_t stream) {
    const int*   ei     = (const int*)d_in[0];
    const int*   et     = (const int*)d_in[1];
    const float* emb    = (const float*)d_in[2];
    const float* basis1 = (const float*)d_in[3];
    const float* comp1  = (const float*)d_in[4];
    const float* root1  = (const float*)d_in[5];
    const float* bias1  = (const float*)d_in[6];
    const float* basis2 = (const float*)d_in[7];
    const float* comp2  = (const float*)d_in[8];
    const float* root2  = (const float*)d_in[9];
    const float* bias2  = (const float*)d_in[10];
    float* out = (float*)d_out;
    (void)in_sizes; (void)n_in; (void)out_size; (void)ws_size;

    char* ws = (char*)d_ws;
    int*            cnt    = (int*)(ws + 0);           // 3,203,072 B
    int*            segoff = (int*)(ws + 3203072);     // 3,203,072 B (post-scatter = ends)
    int*            spk    = (int*)(ws + 6406144);     // 3,200,000 B
    int*            bsum   = (int*)(ws + 9606144);     // 12,512 B
    int*            boff   = (int*)(ws + 9618656);     // 12,512 B
    unsigned short* Bhi1   = (unsigned short*)(ws + 9656320);    // 294,912 B each
    unsigned short* Blo1   = (unsigned short*)(ws + 9951232);
    unsigned short* Bhi2   = (unsigned short*)(ws + 10246144);
    unsigned short* Blo2   = (unsigned short*)(ws + 10541056);
    unsigned short* embh   = (unsigned short*)(ws + 10835968);   // 25.6 MB
    unsigned short* h1h    = (unsigned short*)(ws + 36435968);   // 25.6 MB -> end 62.0 MB

    hipMemsetAsync(cnt, 0, (size_t)NSEG2 * 4, stream);

    k_pre<<<NCVT + NCNT + 2 * NPB, 256, 0, stream>>>(
        emb, embh, ei, et, cnt,
        root1, comp1, basis1, Bhi1, Blo1,
        root2, comp2, basis2, Bhi2, Blo2);

    k_scan_local<<<NSEG2 / 256, 256, 0, stream>>>(cnt, segoff, bsum);
    k_scan_bsum <<<1, 256, 0, stream>>>(bsum, boff);
    k_scan_add  <<<NSEG2 / 256, 256, 0, stream>>>(segoff, boff);
    k_scatter   <<<(EE + 255) / 256, 256, 0, stream>>>(ei, et, segoff, spk);

    k_gemm<true> <<<NBLK, 256, 0, stream>>>(embh, Bhi1, Blo1, bias1, spk, segoff, h1h, nullptr);
    k_gemm<false><<<NBLK, 256, 0, stream>>>(h1h,  Bhi2, Blo2, bias2, spk, segoff, nullptr, out);
}

// Round 12
// 542.661 us; speedup vs baseline: 1.0065x; 1.0065x over previous
//
#include <hip/hip_runtime.h>

#define NN 100000
#define RR 8
#define BB 8
#define DD 128
#define EE 800000
#define KT 1152                  // 128 (root) + 8*128 (relations)
#define NBLK 782                 // ceil(NN/128)
#define NSEG2 (NBLK * 1024)      // 800768 padded segment keys
#define AGSTR 132                // Aagg stride: 66 dwords/row == 2 mod 32 (measured zero-conflict)
#define NCVT 6250                // k_pre partition: cvt blocks
#define NCNT 3125                // k_pre partition: cnt blocks
#define NPB  576                 // k_pre partition: prepB blocks (each layer)

typedef __attribute__((ext_vector_type(8))) __bf16 bf16x8;
typedef __attribute__((ext_vector_type(4))) float f32x4;
typedef __attribute__((ext_vector_type(4))) unsigned int u32x4;

__device__ __forceinline__ unsigned short f2bf(float f) {
    unsigned u = __float_as_uint(f);
    u += 0x7fffu + ((u >> 16) & 1u);          // round-to-nearest-even
    return (unsigned short)(u >> 16);
}
__device__ __forceinline__ float bf2f(unsigned short h) {
    return __uint_as_float(((unsigned)h) << 16);
}

// ---------------------------------------------------------------------------
// prepB body: BT[o][k] bf16 hi/lo; k<128 -> root, else W[r][i][o]
// ---------------------------------------------------------------------------
__device__ __forceinline__ void prepB_body(int idx,
                                           const float* __restrict__ root,
                                           const float* __restrict__ comp,
                                           const float* __restrict__ basis,
                                           unsigned short* __restrict__ Bhi,
                                           unsigned short* __restrict__ Blo) {
    if (idx >= DD * KT) return;
    int o = idx / KT, k = idx - o * KT;
    float v;
    if (k < DD) {
        v = root[k * DD + o];
    } else {
        int r = (k - DD) >> 7, i = (k - DD) & 127;
        float s = 0.f;
#pragma unroll
        for (int b = 0; b < BB; ++b)
            s += comp[r * BB + b] * basis[((size_t)b * DD + i) * DD + o];
        v = s;
    }
    unsigned short hi = f2bf(v);
    Bhi[idx] = hi;
    Blo[idx] = f2bf(v - bf2f(hi));
}

// ---------------------------------------------------------------------------
// Fused preprocessing: cvt | cnt | prepB1 | prepB2 partitioned by blockIdx.
// ---------------------------------------------------------------------------
__global__ __launch_bounds__(256) void k_pre(
    const float* __restrict__ x, unsigned short* __restrict__ xh,
    const int* __restrict__ ei, const int* __restrict__ et, int* __restrict__ cnt,
    const float* __restrict__ root1, const float* __restrict__ comp1,
    const float* __restrict__ basis1,
    unsigned short* __restrict__ Bhi1, unsigned short* __restrict__ Blo1,
    const float* __restrict__ root2, const float* __restrict__ comp2,
    const float* __restrict__ basis2,
    unsigned short* __restrict__ Bhi2, unsigned short* __restrict__ Blo2)
{
    const int blk = blockIdx.x, tid = threadIdx.x;
    if (blk < NCVT) {
        int i = blk * 256 + tid;                 // over NN*DD/8 = 1,600,000
        f32x4 a = ((const f32x4*)x)[2 * i];
        f32x4 b = ((const f32x4*)x)[2 * i + 1];
        u32x4 o;
        o[0] = (unsigned)f2bf(a[0]) | ((unsigned)f2bf(a[1]) << 16);
        o[1] = (unsigned)f2bf(a[2]) | ((unsigned)f2bf(a[3]) << 16);
        o[2] = (unsigned)f2bf(b[0]) | ((unsigned)f2bf(b[1]) << 16);
        o[3] = (unsigned)f2bf(b[2]) | ((unsigned)f2bf(b[3]) << 16);
        ((u32x4*)xh)[i] = o;
    } else if (blk < NCVT + NCNT) {
        int e = (blk - NCVT) * 256 + tid;
        if (e < EE) {
            int d = ei[EE + e];
            atomicAdd(&cnt[(d >> 7) * 1024 + et[e] * 128 + (d & 127)], 1);
        }
    } else if (blk < NCVT + NCNT + NPB) {
        prepB_body((blk - NCVT - NCNT) * 256 + tid, root1, comp1, basis1, Bhi1, Blo1);
    } else {
        prepB_body((blk - NCVT - NCNT - NPB) * 256 + tid, root2, comp2, basis2, Bhi2, Blo2);
    }
}

__global__ __launch_bounds__(256) void k_scan_local(const int* __restrict__ cnt,
                                                    int* __restrict__ loc,
                                                    int* __restrict__ bsum) {
    __shared__ int tmp[256];
    int t = threadIdx.x, i = blockIdx.x * 256 + t;
    int v = cnt[i];
    tmp[t] = v; __syncthreads();
    int val = v;
#pragma unroll
    for (int d = 1; d < 256; d <<= 1) {
        int a = (t >= d) ? tmp[t - d] : 0;
        __syncthreads();
        val += a; tmp[t] = val;
        __syncthreads();
    }
    loc[i] = val - v;
    if (t == 255) bsum[blockIdx.x] = val;
}

__global__ void k_scan_bsum(const int* __restrict__ bsum, int* __restrict__ boff) {
    __shared__ int tmp[256];
    const int NB = NSEG2 / 256;             // 3128
    const int CH = 13;                      // 256*13 >= 3128
    int t = threadIdx.x;
    int base = t * CH, s = 0;
    for (int j = 0; j < CH; ++j) { int idx = base + j; if (idx < NB) s += bsum[idx]; }
    tmp[t] = s; __syncthreads();
    int val = s;
#pragma unroll
    for (int d = 1; d < 256; d <<= 1) {
        int a = (t >= d) ? tmp[t - d] : 0;
        __syncthreads();
        val += a; tmp[t] = val;
        __syncthreads();
    }
    int run = val - s;
    for (int j = 0; j < CH; ++j) { int idx = base + j; if (idx < NB) { boff[idx] = run; run += bsum[idx]; } }
}

__global__ __launch_bounds__(256) void k_scan_add(int* __restrict__ loc,
                                                  const int* __restrict__ boff) {
    int i = blockIdx.x * 256 + threadIdx.x;
    loc[i] += boff[i >> 8];
}

// scatter: pack src; uses segoff as its cursor (post-scatter segoff = segment END,
// segments contiguous in key order so begin[k] = end[k-1])
__global__ __launch_bounds__(256) void k_scatter(const int* __restrict__ ei,
                                                 const int* __restrict__ et,
                                                 int* __restrict__ segoff,
                                                 int* __restrict__ spk) {
    int e = blockIdx.x * 256 + threadIdx.x;
    if (e < EE) {
        int d = ei[EE + e];
        int key = (d >> 7) * 1024 + et[e] * 128 + (d & 127);
        int pos = atomicAdd(&segoff[key], 1);
        spk[pos] = ei[e];
    }
}

// ---------------------------------------------------------------------------
// Fused agg + GEMM, R11 = R10 + 16-bit RELATIVE seg-begin LDS tile.
//  R10 post-mortem: deleting sbeg re-lengthened the per-relation chain to
//  segend->spk->rows (3 hops, ~8-10us/block) — cost more than the conflict
//  fix + 3rd block bought. Fix: sbeg16[1025] = segment begins relative to
//  the block's first edge (block range ~1024+-32 << 65536, ~63-sigma safe),
//  2,052 B. LDS 52,228 B -> still 3 blocks/CU, chain back to 1 hop,
//  conflicts stay 0 (AGSTR=132 class + B ASTR=32 XOR swizzle, both
//  hardware-verified zero).
//  Iron laws: (1) agg transients die before any MFMA (WRITE_SIZE is the
//  spill tripwire); (2) both 32-col agg passes temporally adjacent.
// ---------------------------------------------------------------------------
template <bool WRITE_H1>
__global__ __launch_bounds__(256, 3) void k_gemm(
    const unsigned short* __restrict__ xh,
    const unsigned short* __restrict__ Bhi,
    const unsigned short* __restrict__ Blo,
    const float* __restrict__ bias,
    const int* __restrict__ spk,
    const int* __restrict__ segend,     // post-scatter segoff = segment ends
    unsigned short* __restrict__ h1h,
    float* __restrict__ outf)
{
    __shared__ unsigned short Aagg[128 * AGSTR]; // 33,792 B
    __shared__ unsigned short Bhs[128 * 32];     //  8,192 B
    __shared__ unsigned short Bls[128 * 32];     //  8,192 B
    __shared__ unsigned short sbeg16[1026];      //  2,052 B  (total 52,228)

    const int tid = threadIdx.x;
    const int b = blockIdx.x;
    const int M0 = b * 128;
    const int gbase = b * 1024;

    // ---- seg begins -> LDS, 16-bit relative to block's first edge
    const int beg0 = (gbase == 0) ? 0 : segend[gbase - 1];
    for (int i = tid; i < 1025; i += 256) {
        int v = (gbase + i == 0) ? 0 : segend[gbase + i - 1];
        sbeg16[i] = (unsigned short)(v - beg0);
    }

    const int wave = tid >> 6, lane = tid & 63;
    const int quad = lane >> 4, lm = lane & 15;
    const int node = tid >> 1, half = tid & 1;

    f32x4 acc[2][8];
#pragma unroll
    for (int a = 0; a < 2; ++a)
#pragma unroll
        for (int n = 0; n < 8; ++n) acc[a][n] = (f32x4){0.f, 0.f, 0.f, 0.f};

    // ---- B pipeline: regs always hold the NEXT tile. 16 VGPR.
    const int bro = tid >> 2;                    // 0..63 (also stages 64+bro)
    const int bq = tid & 3;                      // 16B quad within 64B row
    const int bsw = bq ^ ((bro >> 1) & 3);       // swizzled write slot
    const int brd = lm * 32 + (quad ^ ((lm >> 1) & 3)) * 8;  // swizzled read base
    u32x4 bh0, bh1, bl0, bl1;

    auto bload = [&](int k0) {
        bh0 = *(const u32x4*)(Bhi + (size_t)bro * KT + k0 + bq * 8);
        bl0 = *(const u32x4*)(Blo + (size_t)bro * KT + k0 + bq * 8);
        bh1 = *(const u32x4*)(Bhi + (size_t)(64 + bro) * KT + k0 + bq * 8);
        bl1 = *(const u32x4*)(Blo + (size_t)(64 + bro) * KT + k0 + bq * 8);
    };
    auto bwrite = [&]() {
        *(u32x4*)&Bhs[bro * 32 + bsw * 8] = bh0;
        *(u32x4*)&Bls[bro * 32 + bsw * 8] = bl0;
        *(u32x4*)&Bhs[(64 + bro) * 32 + bsw * 8] = bh1;
        *(u32x4*)&Bls[(64 + bro) * 32 + bsw * 8] = bl1;
    };

    auto kstep = [&](bf16x8 af0, bf16x8 af1, int k0next, bool tail) {
#pragma unroll
        for (int nt = 0; nt < 8; ++nt) {
            bf16x8 bh = __builtin_bit_cast(bf16x8, *(const u32x4*)&Bhs[nt * 512 + brd]);
            bf16x8 bl = __builtin_bit_cast(bf16x8, *(const u32x4*)&Bls[nt * 512 + brd]);
            acc[0][nt] = __builtin_amdgcn_mfma_f32_16x16x32_bf16(af0, bh, acc[0][nt], 0, 0, 0);
            acc[0][nt] = __builtin_amdgcn_mfma_f32_16x16x32_bf16(af0, bl, acc[0][nt], 0, 0, 0);
            acc[1][nt] = __builtin_amdgcn_mfma_f32_16x16x32_bf16(af1, bh, acc[1][nt], 0, 0, 0);
            acc[1][nt] = __builtin_amdgcn_mfma_f32_16x16x32_bf16(af1, bl, acc[1][nt], 0, 0, 0);
        }
        if (tail) return;
        __syncthreads();                 // all waves done reading tile t (and Aagg)
        bwrite();                        // LDS <- tile t+1
        if (k0next >= 0) bload(k0next);  // regs <- tile t+2 (flies past barrier)
        __syncthreads();                 // tile t+1 visible
    };

    // ---- prologue: tile 0 -> LDS, tile 1 -> regs
    bload(0);
    bwrite();
    bload(32);

    // root-phase A-fragments (direct global, clamped rows; masked in epilogue)
    int r0 = M0 + wave * 32 + lm;      if (r0 > NN - 1) r0 = NN - 1;
    int r1 = M0 + wave * 32 + 16 + lm; if (r1 > NN - 1) r1 = NN - 1;
    const unsigned short* pa0 = xh + (size_t)r0 * DD + quad * 8;
    const unsigned short* pa1 = xh + (size_t)r1 * DD + quad * 8;

    __syncthreads();                     // tile 0 + sbeg16 visible

    // ---- root phase: 4 k-steps
#pragma unroll
    for (int ks = 0; ks < 4; ++ks) {
        bf16x8 af0 = __builtin_bit_cast(bf16x8, *(const u32x4*)(pa0 + ks * 32));
        bf16x8 af1 = __builtin_bit_cast(bf16x8, *(const u32x4*)(pa1 + ks * 32));
        const int k0n = (ks < 2) ? (ks + 2) * 32 : DD + (ks - 2) * 32;
        kstep(af0, af1, k0n, false);
    }

    // ---- relation phase: agg both halves back-to-back, then 4 k-steps
    for (int r = 0; r < RR; ++r) {
        const int si = r * 128 + node;
        const int rel = (int)sbeg16[si];
        const int beg = beg0 + rel;
        const int cs = (int)sbeg16[si + 1] - rel;

        // (prev kstep's trailing barrier separates these Aagg writes from
        //  relation r-1's MFMA reads)
#pragma unroll
        for (int p = 0; p < 2; ++p) {
            const int coff = half * 64 + p * 32;   // thread's 32-col slice
            float vlo[16], vhi[16];
#pragma unroll
            for (int j = 0; j < 16; ++j) { vlo[j] = 0.f; vhi[j] = 0.f; }

            for (int t = 0; t < cs; ++t) {
                const int sp = spk[beg + t];
                const u32x4* ps = (const u32x4*)(xh + (size_t)sp * DD + coff);
                u32x4 a0 = ps[0], a1 = ps[1], a2 = ps[2], a3 = ps[3];
#pragma unroll
                for (int w = 0; w < 4; ++w) {
                    vlo[w]      += __uint_as_float(a0[w] << 16);
                    vhi[w]      += __uint_as_float(a0[w] & 0xFFFF0000u);
                    vlo[4 + w]  += __uint_as_float(a1[w] << 16);
                    vhi[4 + w]  += __uint_as_float(a1[w] & 0xFFFF0000u);
                    vlo[8 + w]  += __uint_as_float(a2[w] << 16);
                    vhi[8 + w]  += __uint_as_float(a2[w] & 0xFFFF0000u);
                    vlo[12 + w] += __uint_as_float(a3[w] << 16);
                    vhi[12 + w] += __uint_as_float(a3[w] & 0xFFFF0000u);
                }
            }

            const float inv = 1.0f / (float)(cs > 1 ? cs : 1);
            unsigned pk[16];
#pragma unroll
            for (int j = 0; j < 16; ++j)
                pk[j] = (unsigned)f2bf(vlo[j] * inv) | ((unsigned)f2bf(vhi[j] * inv) << 16);
            unsigned short* pw = &Aagg[node * AGSTR + coff];
            *(u32x4*)(pw + 0)  = (u32x4){pk[0],  pk[1],  pk[2],  pk[3]};
            *(u32x4*)(pw + 8)  = (u32x4){pk[4],  pk[5],  pk[6],  pk[7]};
            *(u32x4*)(pw + 16) = (u32x4){pk[8],  pk[9],  pk[10], pk[11]};
            *(u32x4*)(pw + 24) = (u32x4){pk[12], pk[13], pk[14], pk[15]};
        }

        __syncthreads();                 // Aagg ready (B tile already staged)

        // 4 k-steps, A from Aagg
#pragma unroll
        for (int s = 0; s < 4; ++s) {
            bf16x8 af0 = __builtin_bit_cast(bf16x8,
                *(const u32x4*)&Aagg[(wave * 32 + lm) * AGSTR + s * 32 + quad * 8]);
            bf16x8 af1 = __builtin_bit_cast(bf16x8,
                *(const u32x4*)&Aagg[(wave * 32 + 16 + lm) * AGSTR + s * 32 + quad * 8]);
            const bool tail = (r == RR - 1) && (s == 3);
            const int k0n = (s < 2) ? DD + r * 128 + (s + 2) * 32
                          : ((r < RR - 1) ? DD + (r + 1) * 128 + (s - 2) * 32 : -1);
            kstep(af0, af1, k0n, tail);
        }
    }

    // ---- epilogue (C/D: col=lane&15, row=quad*4+reg)
#pragma unroll
    for (int mt = 0; mt < 2; ++mt) {
#pragma unroll
        for (int nt = 0; nt < 8; ++nt) {
            const float bvn = bias[nt * 16 + lm];
#pragma unroll
            for (int rg = 0; rg < 4; ++rg) {
                int row = M0 + wave * 32 + mt * 16 + quad * 4 + rg;
                if (row < NN) {
                    int col = nt * 16 + lm;
                    float v = acc[mt][nt][rg] + bvn;
                    if (WRITE_H1) h1h[(size_t)row * DD + col] = f2bf(fmaxf(v, 0.f));
                    else          outf[(size_t)row * DD + col] = v;
                }
            }
        }
    }
}

// ---------------------------------------------------------------------------

extern "C" void kernel_launch(void* const* d_in, const int* in_sizes, int n_in,
                              void* d_out, int out_size, void* d_ws, size_t ws_size,
                              hipStream_t stream) {
    const int*   ei     = (const int*)d_in[0];
    const int*   et     = (const int*)d_in[1];
    const float* emb    = (const float*)d_in[2];
    const float* basis1 = (const float*)d_in[3];
    const float* comp1  = (const float*)d_in[4];
    const float* root1  = (const float*)d_in[5];
    const float* bias1  = (const float*)d_in[6];
    const float* basis2 = (const float*)d_in[7];
    const float* comp2  = (const float*)d_in[8];
    const float* root2  = (const float*)d_in[9];
    const float* bias2  = (const float*)d_in[10];
    float* out = (float*)d_out;
    (void)in_sizes; (void)n_in; (void)out_size; (void)ws_size;

    char* ws = (char*)d_ws;
    int*            cnt    = (int*)(ws + 0);           // 3,203,072 B
    int*            segoff = (int*)(ws + 3203072);     // 3,203,072 B (post-scatter = ends)
    int*            spk    = (int*)(ws + 6406144);     // 3,200,000 B
    int*            bsum   = (int*)(ws + 9606144);     // 12,512 B
    int*            boff   = (int*)(ws + 9618656);     // 12,512 B
    unsigned short* Bhi1   = (unsigned short*)(ws + 9656320);    // 294,912 B each
    unsigned short* Blo1   = (unsigned short*)(ws + 9951232);
    unsigned short* Bhi2   = (unsigned short*)(ws + 10246144);
    unsigned short* Blo2   = (unsigned short*)(ws + 10541056);
    unsigned short* embh   = (unsigned short*)(ws + 10835968);   // 25.6 MB
    unsigned short* h1h    = (unsigned short*)(ws + 36435968);   // 25.6 MB -> end 62.0 MB

    hipMemsetAsync(cnt, 0, (size_t)NSEG2 * 4, stream);

    k_pre<<<NCVT + NCNT + 2 * NPB, 256, 0, stream>>>(
        emb, embh, ei, et, cnt,
        root1, comp1, basis1, Bhi1, Blo1,
        root2, comp2, basis2, Bhi2, Blo2);

    k_scan_local<<<NSEG2 / 256, 256, 0, stream>>>(cnt, segoff, bsum);
    k_scan_bsum <<<1, 256, 0, stream>>>(bsum, boff);
    k_scan_add  <<<NSEG2 / 256, 256, 0, stream>>>(segoff, boff);
    k_scatter   <<<(EE + 255) / 256, 256, 0, stream>>>(ei, et, segoff, spk);

    k_gemm<true> <<<NBLK, 256, 0, stream>>>(embh, Bhi1, Blo1, bias1, spk, segoff, h1h, nullptr);
    k_gemm<false><<<NBLK, 256, 0, stream>>>(h1h,  Bhi2, Blo2, bias2, spk, segoff, nullptr, out);
}

// Round 13
// 484.359 us; speedup vs baseline: 1.1276x; 1.1204x over previous
//
#include <hip/hip_runtime.h>

#define NN 100000
#define RR 8
#define BB 8
#define DD 128
#define EE 800000
#define KT 1152                  // 128 (root) + 8*128 (relations)
#define BM 64                    // rows per block (R12: was 128)
#define NBLK 1563                // ceil(NN/64)
#define SEGPB 512                // segments per block = RR*BM
#define NSEG2 (NBLK * SEGPB)     // 800,256 padded segment keys (3126*256)
#define AGSTR 132                // Aagg stride: 66 dwords/row (measured zero-conflict class)
#define NCVT 6250                // k_pre partition: cvt blocks
#define NCNT 3125                // k_pre partition: cnt blocks
#define NPB  576                 // k_pre partition: prepB blocks (each layer)

typedef __attribute__((ext_vector_type(8))) __bf16 bf16x8;
typedef __attribute__((ext_vector_type(4))) float f32x4;
typedef __attribute__((ext_vector_type(4))) unsigned int u32x4;

__device__ __forceinline__ unsigned short f2bf(float f) {
    unsigned u = __float_as_uint(f);
    u += 0x7fffu + ((u >> 16) & 1u);          // round-to-nearest-even
    return (unsigned short)(u >> 16);
}
__device__ __forceinline__ float bf2f(unsigned short h) {
    return __uint_as_float(((unsigned)h) << 16);
}

// ---------------------------------------------------------------------------
// prepB body: BT[o][k] bf16 hi/lo; k<128 -> root, else W[r][i][o]
// ---------------------------------------------------------------------------
__device__ __forceinline__ void prepB_body(int idx,
                                           const float* __restrict__ root,
                                           const float* __restrict__ comp,
                                           const float* __restrict__ basis,
                                           unsigned short* __restrict__ Bhi,
                                           unsigned short* __restrict__ Blo) {
    if (idx >= DD * KT) return;
    int o = idx / KT, k = idx - o * KT;
    float v;
    if (k < DD) {
        v = root[k * DD + o];
    } else {
        int r = (k - DD) >> 7, i = (k - DD) & 127;
        float s = 0.f;
#pragma unroll
        for (int b = 0; b < BB; ++b)
            s += comp[r * BB + b] * basis[((size_t)b * DD + i) * DD + o];
        v = s;
    }
    unsigned short hi = f2bf(v);
    Bhi[idx] = hi;
    Blo[idx] = f2bf(v - bf2f(hi));
}

// ---------------------------------------------------------------------------
// Fused preprocessing: cvt | cnt | prepB1 | prepB2 partitioned by blockIdx.
// Sort key (R12, 64-row blocks): (dst>>6)*512 + rel*64 + (dst&63)
// ---------------------------------------------------------------------------
__global__ __launch_bounds__(256) void k_pre(
    const float* __restrict__ x, unsigned short* __restrict__ xh,
    const int* __restrict__ ei, const int* __restrict__ et, int* __restrict__ cnt,
    const float* __restrict__ root1, const float* __restrict__ comp1,
    const float* __restrict__ basis1,
    unsigned short* __restrict__ Bhi1, unsigned short* __restrict__ Blo1,
    const float* __restrict__ root2, const float* __restrict__ comp2,
    const float* __restrict__ basis2,
    unsigned short* __restrict__ Bhi2, unsigned short* __restrict__ Blo2)
{
    const int blk = blockIdx.x, tid = threadIdx.x;
    if (blk < NCVT) {
        int i = blk * 256 + tid;                 // over NN*DD/8 = 1,600,000
        f32x4 a = ((const f32x4*)x)[2 * i];
        f32x4 b = ((const f32x4*)x)[2 * i + 1];
        u32x4 o;
        o[0] = (unsigned)f2bf(a[0]) | ((unsigned)f2bf(a[1]) << 16);
        o[1] = (unsigned)f2bf(a[2]) | ((unsigned)f2bf(a[3]) << 16);
        o[2] = (unsigned)f2bf(b[0]) | ((unsigned)f2bf(b[1]) << 16);
        o[3] = (unsigned)f2bf(b[2]) | ((unsigned)f2bf(b[3]) << 16);
        ((u32x4*)xh)[i] = o;
    } else if (blk < NCVT + NCNT) {
        int e = (blk - NCVT) * 256 + tid;
        if (e < EE) {
            int d = ei[EE + e];
            atomicAdd(&cnt[(d >> 6) * SEGPB + et[e] * BM + (d & 63)], 1);
        }
    } else if (blk < NCVT + NCNT + NPB) {
        prepB_body((blk - NCVT - NCNT) * 256 + tid, root1, comp1, basis1, Bhi1, Blo1);
    } else {
        prepB_body((blk - NCVT - NCNT - NPB) * 256 + tid, root2, comp2, basis2, Bhi2, Blo2);
    }
}

__global__ __launch_bounds__(256) void k_scan_local(const int* __restrict__ cnt,
                                                    int* __restrict__ loc,
                                                    int* __restrict__ bsum) {
    __shared__ int tmp[256];
    int t = threadIdx.x, i = blockIdx.x * 256 + t;
    int v = cnt[i];
    tmp[t] = v; __syncthreads();
    int val = v;
#pragma unroll
    for (int d = 1; d < 256; d <<= 1) {
        int a = (t >= d) ? tmp[t - d] : 0;
        __syncthreads();
        val += a; tmp[t] = val;
        __syncthreads();
    }
    loc[i] = val - v;
    if (t == 255) bsum[blockIdx.x] = val;
}

__global__ void k_scan_bsum(const int* __restrict__ bsum, int* __restrict__ boff) {
    __shared__ int tmp[256];
    const int NB = NSEG2 / 256;             // 3126
    const int CH = 13;                      // 256*13 >= 3126
    int t = threadIdx.x;
    int base = t * CH, s = 0;
    for (int j = 0; j < CH; ++j) { int idx = base + j; if (idx < NB) s += bsum[idx]; }
    tmp[t] = s; __syncthreads();
    int val = s;
#pragma unroll
    for (int d = 1; d < 256; d <<= 1) {
        int a = (t >= d) ? tmp[t - d] : 0;
        __syncthreads();
        val += a; tmp[t] = val;
        __syncthreads();
    }
    int run = val - s;
    for (int j = 0; j < CH; ++j) { int idx = base + j; if (idx < NB) { boff[idx] = run; run += bsum[idx]; } }
}

__global__ __launch_bounds__(256) void k_scan_add(int* __restrict__ loc,
                                                  const int* __restrict__ boff) {
    int i = blockIdx.x * 256 + threadIdx.x;
    loc[i] += boff[i >> 8];
}

// scatter: pack src; uses segoff as its cursor (post-scatter segoff = segment END,
// segments contiguous in key order so begin[k] = end[k-1])
__global__ __launch_bounds__(256) void k_scatter(const int* __restrict__ ei,
                                                 const int* __restrict__ et,
                                                 int* __restrict__ segoff,
                                                 int* __restrict__ spk) {
    int e = blockIdx.x * 256 + threadIdx.x;
    if (e < EE) {
        int d = ei[EE + e];
        int key = (d >> 6) * SEGPB + et[e] * BM + (d & 63);
        int pos = atomicAdd(&segoff[key], 1);
        spk[pos] = ei[e];
    }
}

// ---------------------------------------------------------------------------
// Fused agg + GEMM, R12: M=64 blocks, single-pass 4-threads-per-node agg.
//  R11 isolation: conflicts=0 + 3 blocks/CU + 1-hop chain all landed at
//  ~177us == R9 -> the binding constraint is per-thread serial gather chains
//  at 12 waves/CU. This restructure halves the chain (1 pass, cs iters) and
//  raises parallelism to 4 blocks/CU x 4 waves (LDS 34.3 KB, acc 32 AGPR,
//  launch_bounds(256,4) caps unified regs at 128 — WRITE_SIZE tripwire).
//  * 4 lanes of a node fetch the full 256B row SIMULTANEOUSLY (iron law #2
//    satisfied maximally: one temporal touch).
//  * Wave = (m-half, n-half): rows (wave&1)*32..+31, nt (wave>>1)*4..+3.
//  * B ASTR=32 + XOR quad-swizzle, AGSTR=132 (both measured zero-conflict).
//  * B double-staged reg->LDS pipeline unchanged. Agg transients (48) die
//    before any MFMA (iron law #1).
// ---------------------------------------------------------------------------
template <bool WRITE_H1>
__global__ __launch_bounds__(256, 4) void k_gemm(
    const unsigned short* __restrict__ xh,
    const unsigned short* __restrict__ Bhi,
    const unsigned short* __restrict__ Blo,
    const float* __restrict__ bias,
    const int* __restrict__ spk,
    const int* __restrict__ segend,     // post-scatter segoff = segment ends
    unsigned short* __restrict__ h1h,
    float* __restrict__ outf)
{
    __shared__ unsigned short Aagg[BM * AGSTR];  // 16,896 B
    __shared__ unsigned short Bhs[128 * 32];     //  8,192 B
    __shared__ unsigned short Bls[128 * 32];     //  8,192 B
    __shared__ unsigned short sbeg16[SEGPB + 2]; //  1,028 B  (total 34,308)

    const int tid = threadIdx.x;
    const int b = blockIdx.x;
    const int M0 = b * BM;
    const int gbase = b * SEGPB;

    // ---- seg begins -> LDS, 16-bit relative to block's first edge
    const int beg0 = (gbase == 0) ? 0 : segend[gbase - 1];
    for (int i = tid; i < SEGPB + 1; i += 256) {
        int v = (gbase + i == 0) ? 0 : segend[gbase + i - 1];
        sbeg16[i] = (unsigned short)(v - beg0);
    }

    const int wave = tid >> 6, lane = tid & 63;
    const int quad = lane >> 4, lm = lane & 15;
    const int mh = wave & 1, nh = wave >> 1;     // m-half rows, n-half tiles
    const int node = tid >> 2, cslice = tid & 3; // agg: 4 threads per node

    f32x4 acc[2][4];
#pragma unroll
    for (int a = 0; a < 2; ++a)
#pragma unroll
        for (int n = 0; n < 4; ++n) acc[a][n] = (f32x4){0.f, 0.f, 0.f, 0.f};

    // ---- B pipeline: regs always hold the NEXT tile. 16 VGPR.
    const int bro = tid >> 2;                    // 0..63 (also stages 64+bro)
    const int bq = tid & 3;                      // 16B quad within 64B row
    const int bsw = bq ^ ((bro >> 1) & 3);       // swizzled write slot
    const int brd = lm * 32 + (quad ^ ((lm >> 1) & 3)) * 8;  // swizzled read base
    u32x4 bh0, bh1, bl0, bl1;

    auto bload = [&](int k0) {
        bh0 = *(const u32x4*)(Bhi + (size_t)bro * KT + k0 + bq * 8);
        bl0 = *(const u32x4*)(Blo + (size_t)bro * KT + k0 + bq * 8);
        bh1 = *(const u32x4*)(Bhi + (size_t)(64 + bro) * KT + k0 + bq * 8);
        bl1 = *(const u32x4*)(Blo + (size_t)(64 + bro) * KT + k0 + bq * 8);
    };
    auto bwrite = [&]() {
        *(u32x4*)&Bhs[bro * 32 + bsw * 8] = bh0;
        *(u32x4*)&Bls[bro * 32 + bsw * 8] = bl0;
        *(u32x4*)&Bhs[(64 + bro) * 32 + bsw * 8] = bh1;
        *(u32x4*)&Bls[(64 + bro) * 32 + bsw * 8] = bl1;
    };

    auto kstep = [&](bf16x8 af0, bf16x8 af1, int k0next, bool tail) {
#pragma unroll
        for (int j = 0; j < 4; ++j) {
            const int nt = nh * 4 + j;
            bf16x8 bh = __builtin_bit_cast(bf16x8, *(const u32x4*)&Bhs[nt * 512 + brd]);
            bf16x8 bl = __builtin_bit_cast(bf16x8, *(const u32x4*)&Bls[nt * 512 + brd]);
            acc[0][j] = __builtin_amdgcn_mfma_f32_16x16x32_bf16(af0, bh, acc[0][j], 0, 0, 0);
            acc[0][j] = __builtin_amdgcn_mfma_f32_16x16x32_bf16(af0, bl, acc[0][j], 0, 0, 0);
            acc[1][j] = __builtin_amdgcn_mfma_f32_16x16x32_bf16(af1, bh, acc[1][j], 0, 0, 0);
            acc[1][j] = __builtin_amdgcn_mfma_f32_16x16x32_bf16(af1, bl, acc[1][j], 0, 0, 0);
        }
        if (tail) return;
        __syncthreads();                 // all waves done reading tile t (and Aagg)
        bwrite();                        // LDS <- tile t+1
        if (k0next >= 0) bload(k0next);  // regs <- tile t+2 (flies past barrier)
        __syncthreads();                 // tile t+1 visible
    };

    // ---- prologue: tile 0 -> LDS, tile 1 -> regs
    bload(0);
    bwrite();
    bload(32);

    // root-phase A-fragments (direct global, clamped rows; masked in epilogue)
    int r0 = M0 + mh * 32 + lm;      if (r0 > NN - 1) r0 = NN - 1;
    int r1 = M0 + mh * 32 + 16 + lm; if (r1 > NN - 1) r1 = NN - 1;
    const unsigned short* pa0 = xh + (size_t)r0 * DD + quad * 8;
    const unsigned short* pa1 = xh + (size_t)r1 * DD + quad * 8;

    __syncthreads();                     // tile 0 + sbeg16 visible

    // ---- root phase: 4 k-steps
#pragma unroll
    for (int ks = 0; ks < 4; ++ks) {
        bf16x8 af0 = __builtin_bit_cast(bf16x8, *(const u32x4*)(pa0 + ks * 32));
        bf16x8 af1 = __builtin_bit_cast(bf16x8, *(const u32x4*)(pa1 + ks * 32));
        const int k0n = (ks < 2) ? (ks + 2) * 32 : DD + (ks - 2) * 32;
        kstep(af0, af1, k0n, false);
    }

    // ---- relation phase: single-pass agg (4 threads/node), then 4 k-steps
    for (int r = 0; r < RR; ++r) {
        const int si = r * BM + node;
        const int rel0 = (int)sbeg16[si];
        const int beg = beg0 + rel0;
        const int cs = (int)sbeg16[si + 1] - rel0;

        // (prev kstep's trailing barrier separates these Aagg writes from
        //  relation r-1's MFMA reads)
        const int coff = cslice * 32;        // thread's 32-col slice
        {
            float vlo[16], vhi[16];
#pragma unroll
            for (int j = 0; j < 16; ++j) { vlo[j] = 0.f; vhi[j] = 0.f; }

            for (int t = 0; t < cs; ++t) {
                const int sp = spk[beg + t];
                const u32x4* ps = (const u32x4*)(xh + (size_t)sp * DD + coff);
                u32x4 a0 = ps[0], a1 = ps[1], a2 = ps[2], a3 = ps[3];
#pragma unroll
                for (int w = 0; w < 4; ++w) {
                    vlo[w]      += __uint_as_float(a0[w] << 16);
                    vhi[w]      += __uint_as_float(a0[w] & 0xFFFF0000u);
                    vlo[4 + w]  += __uint_as_float(a1[w] << 16);
                    vhi[4 + w]  += __uint_as_float(a1[w] & 0xFFFF0000u);
                    vlo[8 + w]  += __uint_as_float(a2[w] << 16);
                    vhi[8 + w]  += __uint_as_float(a2[w] & 0xFFFF0000u);
                    vlo[12 + w] += __uint_as_float(a3[w] << 16);
                    vhi[12 + w] += __uint_as_float(a3[w] & 0xFFFF0000u);
                }
            }

            const float inv = 1.0f / (float)(cs > 1 ? cs : 1);
            unsigned pk[16];
#pragma unroll
            for (int j = 0; j < 16; ++j)
                pk[j] = (unsigned)f2bf(vlo[j] * inv) | ((unsigned)f2bf(vhi[j] * inv) << 16);
            unsigned short* pw = &Aagg[node * AGSTR + coff];
            *(u32x4*)(pw + 0)  = (u32x4){pk[0],  pk[1],  pk[2],  pk[3]};
            *(u32x4*)(pw + 8)  = (u32x4){pk[4],  pk[5],  pk[6],  pk[7]};
            *(u32x4*)(pw + 16) = (u32x4){pk[8],  pk[9],  pk[10], pk[11]};
            *(u32x4*)(pw + 24) = (u32x4){pk[12], pk[13], pk[14], pk[15]};
        }

        __syncthreads();                 // Aagg ready (B tile already staged)

        // 4 k-steps, A from Aagg
#pragma unroll
        for (int s = 0; s < 4; ++s) {
            bf16x8 af0 = __builtin_bit_cast(bf16x8,
                *(const u32x4*)&Aagg[(mh * 32 + lm) * AGSTR + s * 32 + quad * 8]);
            bf16x8 af1 = __builtin_bit_cast(bf16x8,
                *(const u32x4*)&Aagg[(mh * 32 + 16 + lm) * AGSTR + s * 32 + quad * 8]);
            const bool tail = (r == RR - 1) && (s == 3);
            const int k0n = (s < 2) ? DD + r * 128 + (s + 2) * 32
                          : ((r < RR - 1) ? DD + (r + 1) * 128 + (s - 2) * 32 : -1);
            kstep(af0, af1, k0n, tail);
        }
    }

    // ---- epilogue (C/D: col=lane&15, row=quad*4+reg)
#pragma unroll
    for (int mt = 0; mt < 2; ++mt) {
#pragma unroll
        for (int j = 0; j < 4; ++j) {
            const int nt = nh * 4 + j;
            const float bvn = bias[nt * 16 + lm];
#pragma unroll
            for (int rg = 0; rg < 4; ++rg) {
                int row = M0 + mh * 32 + mt * 16 + quad * 4 + rg;
                if (row < NN) {
                    int col = nt * 16 + lm;
                    float v = acc[mt][j][rg] + bvn;
                    if (WRITE_H1) h1h[(size_t)row * DD + col] = f2bf(fmaxf(v, 0.f));
                    else          outf[(size_t)row * DD + col] = v;
                }
            }
        }
    }
}

// ---------------------------------------------------------------------------

extern "C" void kernel_launch(void* const* d_in, const int* in_sizes, int n_in,
                              void* d_out, int out_size, void* d_ws, size_t ws_size,
                              hipStream_t stream) {
    const int*   ei     = (const int*)d_in[0];
    const int*   et     = (const int*)d_in[1];
    const float* emb    = (const float*)d_in[2];
    const float* basis1 = (const float*)d_in[3];
    const float* comp1  = (const float*)d_in[4];
    const float* root1  = (const float*)d_in[5];
    const float* bias1  = (const float*)d_in[6];
    const float* basis2 = (const float*)d_in[7];
    const float* comp2  = (const float*)d_in[8];
    const float* root2  = (const float*)d_in[9];
    const float* bias2  = (const float*)d_in[10];
    float* out = (float*)d_out;
    (void)in_sizes; (void)n_in; (void)out_size; (void)ws_size;

    char* ws = (char*)d_ws;
    int*            cnt    = (int*)(ws + 0);           // 3,201,024 B used
    int*            segoff = (int*)(ws + 3203072);     // (post-scatter = ends)
    int*            spk    = (int*)(ws + 6406144);     // 3,200,000 B
    int*            bsum   = (int*)(ws + 9606144);     // 12,504 B used
    int*            boff   = (int*)(ws + 9618656);     // 12,504 B used
    unsigned short* Bhi1   = (unsigned short*)(ws + 9656320);    // 294,912 B each
    unsigned short* Blo1   = (unsigned short*)(ws + 9951232);
    unsigned short* Bhi2   = (unsigned short*)(ws + 10246144);
    unsigned short* Blo2   = (unsigned short*)(ws + 10541056);
    unsigned short* embh   = (unsigned short*)(ws + 10835968);   // 25.6 MB
    unsigned short* h1h    = (unsigned short*)(ws + 36435968);   // 25.6 MB -> end 62.0 MB

    hipMemsetAsync(cnt, 0, (size_t)NSEG2 * 4, stream);

    k_pre<<<NCVT + NCNT + 2 * NPB, 256, 0, stream>>>(
        emb, embh, ei, et, cnt,
        root1, comp1, basis1, Bhi1, Blo1,
        root2, comp2, basis2, Bhi2, Blo2);

    k_scan_local<<<NSEG2 / 256, 256, 0, stream>>>(cnt, segoff, bsum);
    k_scan_bsum <<<1, 256, 0, stream>>>(bsum, boff);
    k_scan_add  <<<NSEG2 / 256, 256, 0, stream>>>(segoff, boff);
    k_scatter   <<<(EE + 255) / 256, 256, 0, stream>>>(ei, et, segoff, spk);

    k_gemm<true> <<<NBLK, 256, 0, stream>>>(embh, Bhi1, Blo1, bias1, spk, segoff, h1h, nullptr);
    k_gemm<false><<<NBLK, 256, 0, stream>>>(h1h,  Bhi2, Blo2, bias2, spk, segoff, nullptr, out);
}